// Round 5
// baseline (171.639 us; speedup 1.0000x reference)
//
#include <hip/hip_runtime.h>

// RoutingAttention gfx950 — R14 (bisect, part 2).
// R13 proved the 4-stage pipelined-W skeleton correct (oproj passed with it).
// Now split proj: qkproj = VERBATIM R10 proj for modes 0,1 (proven);
// vproj = pipelined skeleton + V^T Lt epilogue ONLY (the piece under test).
// attn (register P-path) and oproj (pipelined) unchanged from R13.
// B=2 P=8 S=1024 C=256 NH=8 DK=32; T=16384; NW=128.

typedef _Float16 half8 __attribute__((ext_vector_type(8)));
typedef _Float16 half4 __attribute__((ext_vector_type(4)));
typedef float f32x4 __attribute__((ext_vector_type(4)));

#if __has_builtin(__builtin_amdgcn_exp2f)
#define EXP2F(x) __builtin_amdgcn_exp2f(x)
#else
#define EXP2F(x) exp2f(x)
#endif

__device__ __forceinline__ f32x4 mfma16(half8 a, half8 b, f32x4 c) {
  return __builtin_amdgcn_mfma_f32_16x16x32_f16(a, b, c, 0, 0, 0);
}

__device__ __forceinline__ int pk2(float a, float b) {
  auto h = __builtin_amdgcn_cvt_pkrtz(a, b);
  return __builtin_bit_cast(int, h);
}

__device__ __forceinline__ half8 cvt8(float4 f0, float4 f1) {
  union { int i[4]; half8 h; } u;
  u.i[0] = pk2(f0.x, f0.y); u.i[1] = pk2(f0.z, f0.w);
  u.i[2] = pk2(f1.x, f1.y); u.i[3] = pk2(f1.z, f1.w);
  return u.h;
}

__device__ __forceinline__ half8 cvt8v(f32x4 f0, f32x4 f1) {
  union { int i[4]; half8 h; } u;
  u.i[0] = pk2(f0[0], f0[1]); u.i[1] = pk2(f0[2], f0[3]);
  u.i[2] = pk2(f1[0], f1[1]); u.i[3] = pk2(f1[2], f1[3]);
  return u.h;
}

// async global->LDS, 16B per lane; lds dest = wave-uniform base + lane*16
__device__ __forceinline__ void g2lds16(const _Float16* g, _Float16* l) {
  __builtin_amdgcn_global_load_lds(
      (const __attribute__((address_space(1))) void*)g,
      (__attribute__((address_space(3))) void*)l, 16, 0, 0);
}

// ws layout (halves)
static constexpr size_t QH_OFF  = 0;          // (win,s,dk), q scaled log2(e)/sqrt(32)
static constexpr size_t KH_OFF  = 4194304;    // (win,s,dk)
static constexpr size_t VT_OFF  = 8388608;    // (win,dk,s)
static constexpr size_t CTX_OFF = 12582912;   // (tok,C)
static constexpr size_t WF_OFF  = 16777216;   // 4 mats frag-contiguous fp16

// ---------------- W prep: fp32 -> fp16 frag-contiguous ----------------
__global__ __launch_bounds__(256) void prep_kernel(
    const float* __restrict__ wq, const float* __restrict__ wk,
    const float* __restrict__ wv, const float* __restrict__ wo,
    _Float16* __restrict__ ws)
{
  int u = blockIdx.x * 256 + threadIdx.x;          // 0..32767
  int lane = u & 63, ks = (u >> 6) & 7, nt = (u >> 9) & 15, mat = u >> 13;
  const float* W = (mat == 0) ? wq : (mat == 1) ? wk : (mat == 2) ? wv : wo;
  const float* p = W + (size_t)(nt * 16 + (lane & 15)) * 256 + ks * 32 + (lane >> 4) * 8;
  half8 h = cvt8(*(const float4*)p, *(const float4*)(p + 4));
  *(half8*)(ws + WF_OFF + (size_t)u * 8) = h;
}

// ---------------- Q/K projection (VERBATIM R10 proj, modes 0/1) -------------
__global__ __launch_bounds__(256, 2) void qkproj_kernel(
    const float* __restrict__ xq, const float* __restrict__ xk,
    const float* __restrict__ bq, const float* __restrict__ bk,
    _Float16* __restrict__ ws)
{
  __shared__ __align__(16) _Float16 Wb[32768];   // 64KB: B tiles, then epilogue

  int mode = blockIdx.z;
  const float* X  = (mode == 0) ? xq : xk;
  const float* bias = (mode == 0) ? bq : bk;
  const _Float16* WFs = ws + WF_OFF + (size_t)mode * 65536
                        + (size_t)blockIdx.y * 32768;   // 8-ntg slice
  _Float16* outp = ws + ((mode == 0) ? QH_OFF : KH_OFF);
  const float scale = (mode == 0) ? 0.2550348654f : 1.0f;  // log2(e)/sqrt(32)

  int tid = threadIdx.x, lane = tid & 63, wid = tid >> 6;
  int l16 = lane & 15, quad = lane >> 4;
  int widm = wid >> 1, widn = wid & 1;
  int m0 = blockIdx.x * 64;

  const float* r0 = X + (size_t)(m0 + widm * 32 + l16) * 256 + quad * 8;
  const float* r1 = r0 + 16 * 256;
  float4 a0[8][2], a1[8][2];
#pragma unroll
  for (int ks = 0; ks < 8; ++ks) {
    a0[ks][0] = *(const float4*)(r0 + ks * 32);
    a0[ks][1] = *(const float4*)(r0 + ks * 32 + 4);
    a1[ks][0] = *(const float4*)(r1 + ks * 32);
    a1[ks][1] = *(const float4*)(r1 + ks * 32 + 4);
  }
#pragma unroll
  for (int i = 0; i < 16; ++i) {
    int off = wid * 8192 + i * 512;
    g2lds16(WFs + off + lane * 8, Wb + off);
  }

  half8 a16[2][8];
#pragma unroll
  for (int ks = 0; ks < 8; ++ks) {
    a16[0][ks] = cvt8(a0[ks][0], a0[ks][1]);
    a16[1][ks] = cvt8(a1[ks][0], a1[ks][1]);
  }
  f32x4 acc[2][4] = {};
  __syncthreads();

#pragma unroll
  for (int ks = 0; ks < 8; ++ks) {
    half8 bf[4];
#pragma unroll
    for (int t = 0; t < 4; ++t)
      bf[t] = *(const half8*)(Wb + ((size_t)(widn * 4 + t) * 8 + ks) * 512 + lane * 8);
#pragma unroll
    for (int mt = 0; mt < 2; ++mt)
#pragma unroll
      for (int t = 0; t < 4; ++t)
        acc[mt][t] = mfma16(a16[mt][ks], bf[t], acc[mt][t]);
  }

  __syncthreads();
  int b = m0 >> 13, p = (m0 >> 10) & 7, s0 = m0 & 1023;
  _Float16* Lt = Wb;                   // [64][136]
#pragma unroll
  for (int mt = 0; mt < 2; ++mt)
#pragma unroll
    for (int t = 0; t < 4; ++t) {
      int ncol = widn * 64 + t * 16 + l16;
      float bval = bias[blockIdx.y * 128 + ncol];
#pragma unroll
      for (int r = 0; r < 4; ++r)
        Lt[(widm * 32 + mt * 16 + quad * 4 + r) * 136 + ncol] =
            (_Float16)((acc[mt][t][r] + bval) * scale);
    }
  __syncthreads();
#pragma unroll
  for (int j = 0; j < 4; ++j) {
    int seg = j * 64 + (tid >> 2), sub = tid & 3;
    int s = seg & 63, hloc = seg >> 6;
    int h = blockIdx.y * 4 + hloc;
    half8 v = *(const half8*)(Lt + s * 136 + hloc * 32 + sub * 8);
    size_t wbase = (size_t)((b * 8 + h) * 8 + p) * 32768;
    *(half8*)(outp + wbase + (size_t)(s0 + s) * 32 + sub * 8) = v;
  }
}

// ---------------- V projection: pipelined skeleton + V^T epilogue -----------
// Skeleton proven by R13's oproj; the V^T Lt transpose epilogue is the piece
// under test (the only remaining unproven code from R12's proj).
__global__ __launch_bounds__(256, 3) void vproj_kernel(
    const float* __restrict__ xv, const float* __restrict__ bv,
    _Float16* __restrict__ ws)
{
  __shared__ __align__(16) _Float16 Wb[16384 + 4608];  // 32KB W stage + 9KB Lt
  _Float16* Lt = Wb + 16384;
  const _Float16* WFm = ws + WF_OFF + (size_t)2 * 65536;
  _Float16* outp = ws + VT_OFF;

  int tid = threadIdx.x, lane = tid & 63, wid = tid >> 6;
  int l16 = lane & 15, quad = lane >> 4;
  int m0 = blockIdx.x * 64;
  int b = m0 >> 13, p = (m0 >> 10) & 7, s0 = m0 & 1023;

#pragma unroll
  for (int it = 0; it < 8; ++it)
    g2lds16(WFm + it * 2048 + wid * 512 + lane * 8, Wb + it * 2048 + wid * 512);

  const float* r0 = xv + (size_t)(m0 + wid * 16 + l16) * 256 + quad * 8;
  float4 xa[8][2];
#pragma unroll
  for (int ks = 0; ks < 8; ++ks) {
    xa[ks][0] = *(const float4*)(r0 + ks * 32);
    xa[ks][1] = *(const float4*)(r0 + ks * 32 + 4);
  }
  half8 a16[8];
#pragma unroll
  for (int ks = 0; ks < 8; ++ks) a16[ks] = cvt8(xa[ks][0], xa[ks][1]);

  for (int s = 0; s < 4; ++s) {
    __syncthreads();                       // W stage s resident (drains g2lds)
    f32x4 acc[4] = {};
#pragma unroll
    for (int ks = 0; ks < 8; ++ks)
#pragma unroll
      for (int t = 0; t < 4; ++t) {
        half8 bf = *(const half8*)(Wb + ((size_t)(t * 8 + ks)) * 512 + lane * 8);
        acc[t] = mfma16(a16[ks], bf, acc[t]);
      }
    // V^T: Lt[col][row], stride 72 (rows 16B-aligned)
#pragma unroll
    for (int t = 0; t < 4; ++t) {
      float bval = bv[s * 64 + t * 16 + l16];
      half4 h4;
#pragma unroll
      for (int r = 0; r < 4; ++r) h4[r] = (_Float16)(acc[t][r] + bval);
      *(half4*)(Lt + (t * 16 + l16) * 72 + wid * 16 + quad * 4) = h4;
    }
    __syncthreads();                       // Lt ready AND all waves done w/ Wb
    if (s < 3) {
#pragma unroll
      for (int it = 0; it < 8; ++it)
        g2lds16(WFm + (size_t)(s + 1) * 16384 + it * 2048 + wid * 512 + lane * 8,
                Wb + it * 2048 + wid * 512);
    }
#pragma unroll
    for (int j = 0; j < 2; ++j) {
      int chunk = j * 256 + tid;
      int col = chunk >> 3, r8 = chunk & 7;
      half8 v = *(const half8*)(Lt + col * 72 + r8 * 8);
      int o = s * 64 + col;
      int h = o >> 5, dki = o & 31;
      size_t wbase = (size_t)((b * 8 + h) * 8 + p) * 32768;
      *(half8*)(outp + wbase + (size_t)dki * 1024 + s0 + r8 * 8) = v;
    }
  }
}

// ---------------- attention: wave split-K, exp2-direct, REGISTER P-path -----
__global__ __launch_bounds__(256, 3) void attn_kernel(
    const _Float16* __restrict__ ws, _Float16* __restrict__ ctx)
{
  __shared__ __align__(16) unsigned char smem[18432];  // epilogue only

  int tid = threadIdx.x, lane = tid & 63, wid = tid >> 6;
  int l16 = lane & 15, quad = lane >> 4;
  int w = blockIdx.x & 127, qc = blockIdx.x >> 7;  // XCD-clustered; qc 0..15
  int b = w >> 6, h = (w >> 3) & 7, p = w & 7;
  const _Float16* qhw = ws + QH_OFF + (size_t)w * 32768;
  const _Float16* khw = ws + KH_OFF + (size_t)w * 32768;
  const _Float16* vtw = ws + VT_OFF + (size_t)w * 32768;
  int qrow0 = qc * 64;

  half8 qf[4];
#pragma unroll
  for (int g = 0; g < 4; ++g)
    qf[g] = *(const half8*)(qhw + (size_t)(qrow0 + g * 16 + l16) * 32 + quad * 8);

  // ones A-frag: row m=0 only -> lsum lands in C row 0 (quad==0, reg 0)
  half8 ones = {};
  if (l16 == 0) {
#pragma unroll
    for (int j = 0; j < 8; ++j) ones[j] = (_Float16)1.0f;
  }

  // permuted K row indices: A-row m holds k = (m>>2)*8 + (m&3) (+4 for kc1)
  int kp0 = ((l16 >> 2) << 3) + (l16 & 3);
  int kp1 = kp0 + 4;

  f32x4 Ot[2][4] = {};      // [dk-tile][q-group] O^T partials
  f32x4 Lacc[4] = {};       // lsum partials via ones-row MFMA
  int kbase = wid * 256;

  half8 kc0 = *(const half8*)(khw + (size_t)(kbase + kp0) * 32 + quad * 8);
  half8 kc1 = *(const half8*)(khw + (size_t)(kbase + kp1) * 32 + quad * 8);
  half8 vc0 = *(const half8*)(vtw + (size_t)l16 * 1024 + kbase + quad * 8);
  half8 vc1 = *(const half8*)(vtw + (size_t)(16 + l16) * 1024 + kbase + quad * 8);

  for (int kk = 0; kk < 8; ++kk) {
    int kn = kbase + (((kk + 1) & 7) << 5);
    half8 kn0 = *(const half8*)(khw + (size_t)(kn + kp0) * 32 + quad * 8);
    half8 kn1 = *(const half8*)(khw + (size_t)(kn + kp1) * 32 + quad * 8);
    half8 vn0 = *(const half8*)(vtw + (size_t)l16 * 1024 + kn + quad * 8);
    half8 vn1 = *(const half8*)(vtw + (size_t)(16 + l16) * 1024 + kn + quad * 8);

    f32x4 z = {0.f, 0.f, 0.f, 0.f};
#pragma unroll
    for (int g = 0; g < 4; ++g) {
      f32x4 St0 = mfma16(kc0, qf[g], z);
      f32x4 St1 = mfma16(kc1, qf[g], z);
      f32x4 p0, p1;
#pragma unroll
      for (int r = 0; r < 4; ++r) {
        p0[r] = EXP2F(St0[r]);
        p1[r] = EXP2F(St1[r]);
      }
      half8 pf = cvt8v(p0, p1);          // B[k=quad*8+j][q=l16] directly
      Ot[0][g] = mfma16(vc0, pf, Ot[0][g]);
      Ot[1][g] = mfma16(vc1, pf, Ot[1][g]);
      Lacc[g]  = mfma16(ones, pf, Lacc[g]);
    }
    kc0 = kn0; kc1 = kn1; vc0 = vn0; vc1 = vn1;
  }

  // ---- cross-wave merge (LDS: fp16 Of + Ls) ----
  __syncthreads();
  unsigned int* Of16 = (unsigned int*)smem;        // [4][64][17] u32 (fp16x2)
  float* Ls = (float*)(smem + 17408);              // [4][64]
  if (quad == 0) {
#pragma unroll
    for (int g = 0; g < 4; ++g) Ls[wid * 64 + g * 16 + l16] = Lacc[g][0];
  }
#pragma unroll
  for (int d = 0; d < 2; ++d)
#pragma unroll
    for (int g = 0; g < 4; ++g) {
      int base = wid * 1088 + (g * 16 + l16) * 17 + d * 8 + quad * 2;
      Of16[base]     = pk2(Ot[d][g][0], Ot[d][g][1]);
      Of16[base + 1] = pk2(Ot[d][g][2], Ot[d][g][3]);
    }
  __syncthreads();

  int q = tid >> 2, c = tid & 3;
  float lt = Ls[q] + Ls[64 + q] + Ls[128 + q] + Ls[192 + q];
  float linv = 1.0f / lt;
  union { int i[4]; half8 hh; } u;
#pragma unroll
  for (int jj = 0; jj < 4; ++jj) {
    int idx = q * 17 + c * 4 + jj;
    float sa = 0.f, sb = 0.f;
#pragma unroll
    for (int ww = 0; ww < 4; ++ww) {
      union { unsigned int x; _Float16 h2[2]; } cv;
      cv.x = Of16[ww * 1088 + idx];
      sa += (float)cv.h2[0]; sb += (float)cv.h2[1];
    }
    u.i[jj] = pk2(sa * linv, sb * linv);
  }
  size_t tok = (size_t)(b * 8 + p) * 1024 + qrow0 + q;
  *(half8*)(ctx + tok * 256 + h * 32 + c * 8) = u.hh;
}

// ---------------- output projection: out = ctx @ Wo^T + bo (fp32) -----------
// 4-stage streamed-W structure (proven R13); ctx read once; direct stores.
__global__ __launch_bounds__(256, 4) void oproj_kernel(
    const _Float16* __restrict__ ws, const float* __restrict__ bo,
    float* __restrict__ out)
{
  __shared__ __align__(16) _Float16 Wb[16384];

  int tid = threadIdx.x, lane = tid & 63, wid = tid >> 6;
  int l16 = lane & 15, quad = lane >> 4;
  int m0 = blockIdx.x * 64;
  const _Float16* A = ws + CTX_OFF;
  const _Float16* WF3 = ws + WF_OFF + (size_t)3 * 65536;

#pragma unroll
  for (int it = 0; it < 8; ++it)
    g2lds16(WF3 + it * 2048 + wid * 512 + lane * 8, Wb + it * 2048 + wid * 512);

  const _Float16* r0 = A + (size_t)(m0 + wid * 16 + l16) * 256 + quad * 8;
  half8 a16[8];
#pragma unroll
  for (int ks = 0; ks < 8; ++ks) a16[ks] = *(const half8*)(r0 + ks * 32);

  for (int s = 0; s < 4; ++s) {
    __syncthreads();                       // W stage s resident
    f32x4 acc[4] = {};
#pragma unroll
    for (int ks = 0; ks < 8; ++ks)
#pragma unroll
      for (int t = 0; t < 4; ++t) {
        half8 bf = *(const half8*)(Wb + ((size_t)(t * 8 + ks)) * 512 + lane * 8);
        acc[t] = mfma16(a16[ks], bf, acc[t]);
      }
    __syncthreads();                       // all waves done with Wb
    if (s < 3) {
#pragma unroll
      for (int it = 0; it < 8; ++it)
        g2lds16(WF3 + (size_t)(s + 1) * 16384 + it * 2048 + wid * 512 + lane * 8,
                Wb + it * 2048 + wid * 512);
    }
#pragma unroll
    for (int t = 0; t < 4; ++t) {
      int o = s * 64 + t * 16 + l16;
      float bval = bo[o];
#pragma unroll
      for (int r = 0; r < 4; ++r)
        out[(size_t)(m0 + wid * 16 + quad * 4 + r) * 256 + o] = acc[t][r] + bval;
    }
  }
}

extern "C" void kernel_launch(void* const* d_in, const int* in_sizes, int n_in,
                              void* d_out, int out_size, void* d_ws, size_t ws_size,
                              hipStream_t stream)
{
  const float* q  = (const float*)d_in[0];
  const float* k  = (const float*)d_in[1];
  const float* v  = (const float*)d_in[2];
  const float* Wq = (const float*)d_in[3];
  const float* bq = (const float*)d_in[4];
  const float* Wk = (const float*)d_in[5];
  const float* bk = (const float*)d_in[6];
  const float* Wv = (const float*)d_in[7];
  const float* bv = (const float*)d_in[8];
  const float* Wo = (const float*)d_in[9];
  const float* bo = (const float*)d_in[10];
  _Float16* ws = (_Float16*)d_ws;
  float* out = (float*)d_out;

  prep_kernel<<<128, 256, 0, stream>>>(Wq, Wk, Wv, Wo, ws);
  qkproj_kernel<<<dim3(256, 2, 2), 256, 0, stream>>>(q, k, bq, bk, ws);
  vproj_kernel<<<256, 256, 0, stream>>>(v, bv, ws);
  attn_kernel<<<2048, 256, 0, stream>>>(ws, ws + CTX_OFF);   // 128 win x 16 qc
  oproj_kernel<<<256, 256, 0, stream>>>(ws, bo, out);
}

// Round 6
// 161.019 us; speedup vs baseline: 1.0660x; 1.0660x over previous
//
#include <hip/hip_runtime.h>

// RoutingAttention gfx950 — R15.
// Bisect R13/R14 proved: pipelined 4-stage skeleton correct (oproj, vproj).
// R11/R12 failures isolated to the dual-epilogue in-loop branch (CFG), not
// the Q/K epilogue math. R15: qkproj rebuilt in the proven single-epilogue
// skeleton (entry-level mode select like R10), X read ONCE per tensor,
// 3 blocks/CU. vproj/attn/oproj unchanged from R14.
// B=2 P=8 S=1024 C=256 NH=8 DK=32; T=16384; NW=128.

typedef _Float16 half8 __attribute__((ext_vector_type(8)));
typedef _Float16 half4 __attribute__((ext_vector_type(4)));
typedef float f32x4 __attribute__((ext_vector_type(4)));

#if __has_builtin(__builtin_amdgcn_exp2f)
#define EXP2F(x) __builtin_amdgcn_exp2f(x)
#else
#define EXP2F(x) exp2f(x)
#endif

__device__ __forceinline__ f32x4 mfma16(half8 a, half8 b, f32x4 c) {
  return __builtin_amdgcn_mfma_f32_16x16x32_f16(a, b, c, 0, 0, 0);
}

__device__ __forceinline__ int pk2(float a, float b) {
  auto h = __builtin_amdgcn_cvt_pkrtz(a, b);
  return __builtin_bit_cast(int, h);
}

__device__ __forceinline__ half8 cvt8(float4 f0, float4 f1) {
  union { int i[4]; half8 h; } u;
  u.i[0] = pk2(f0.x, f0.y); u.i[1] = pk2(f0.z, f0.w);
  u.i[2] = pk2(f1.x, f1.y); u.i[3] = pk2(f1.z, f1.w);
  return u.h;
}

__device__ __forceinline__ half8 cvt8v(f32x4 f0, f32x4 f1) {
  union { int i[4]; half8 h; } u;
  u.i[0] = pk2(f0[0], f0[1]); u.i[1] = pk2(f0[2], f0[3]);
  u.i[2] = pk2(f1[0], f1[1]); u.i[3] = pk2(f1[2], f1[3]);
  return u.h;
}

// async global->LDS, 16B per lane; lds dest = wave-uniform base + lane*16
__device__ __forceinline__ void g2lds16(const _Float16* g, _Float16* l) {
  __builtin_amdgcn_global_load_lds(
      (const __attribute__((address_space(1))) void*)g,
      (__attribute__((address_space(3))) void*)l, 16, 0, 0);
}

// ws layout (halves)
static constexpr size_t QH_OFF  = 0;          // (win,s,dk), q scaled log2(e)/sqrt(32)
static constexpr size_t KH_OFF  = 4194304;    // (win,s,dk)
static constexpr size_t VT_OFF  = 8388608;    // (win,dk,s)
static constexpr size_t CTX_OFF = 12582912;   // (tok,C)
static constexpr size_t WF_OFF  = 16777216;   // 4 mats frag-contiguous fp16

// ---------------- W prep: fp32 -> fp16 frag-contiguous ----------------
__global__ __launch_bounds__(256) void prep_kernel(
    const float* __restrict__ wq, const float* __restrict__ wk,
    const float* __restrict__ wv, const float* __restrict__ wo,
    _Float16* __restrict__ ws)
{
  int u = blockIdx.x * 256 + threadIdx.x;          // 0..32767
  int lane = u & 63, ks = (u >> 6) & 7, nt = (u >> 9) & 15, mat = u >> 13;
  const float* W = (mat == 0) ? wq : (mat == 1) ? wk : (mat == 2) ? wv : wo;
  const float* p = W + (size_t)(nt * 16 + (lane & 15)) * 256 + ks * 32 + (lane >> 4) * 8;
  half8 h = cvt8(*(const float4*)p, *(const float4*)(p + 4));
  *(half8*)(ws + WF_OFF + (size_t)u * 8) = h;
}

// ---------------- Q/K projection: pipelined skeleton + Q/K epilogue ---------
// Single epilogue variant in the stage loop (CFG matches proven vproj).
// mode (q vs k) selected at entry only. X read once; W streamed 4x32KB.
__global__ __launch_bounds__(256, 3) void qkproj_kernel(
    const float* __restrict__ xq, const float* __restrict__ xk,
    const float* __restrict__ bq, const float* __restrict__ bk,
    _Float16* __restrict__ ws)
{
  __shared__ __align__(16) _Float16 Wb[16384 + 4608];  // 32KB W stage + 9KB Lt
  _Float16* Lt = Wb + 16384;

  int mode = blockIdx.y;                 // 0=q, 1=k
  const float* X  = mode ? xk : xq;
  const float* bias = mode ? bk : bq;
  const _Float16* WFm = ws + WF_OFF + (size_t)mode * 65536;
  _Float16* outp = ws + (mode ? KH_OFF : QH_OFF);
  const float scale = mode ? 1.0f : 0.2550348654f;  // log2(e)/sqrt(32)

  int tid = threadIdx.x, lane = tid & 63, wid = tid >> 6;
  int l16 = lane & 15, quad = lane >> 4;
  int m0 = blockIdx.x * 64;
  int b = m0 >> 13, p = (m0 >> 10) & 7, s0 = m0 & 1023;

#pragma unroll
  for (int it = 0; it < 8; ++it)
    g2lds16(WFm + it * 2048 + wid * 512 + lane * 8, Wb + it * 2048 + wid * 512);

  const float* r0 = X + (size_t)(m0 + wid * 16 + l16) * 256 + quad * 8;
  float4 xa[8][2];
#pragma unroll
  for (int ks = 0; ks < 8; ++ks) {
    xa[ks][0] = *(const float4*)(r0 + ks * 32);
    xa[ks][1] = *(const float4*)(r0 + ks * 32 + 4);
  }
  half8 a16[8];
#pragma unroll
  for (int ks = 0; ks < 8; ++ks) a16[ks] = cvt8(xa[ks][0], xa[ks][1]);

  for (int s = 0; s < 4; ++s) {
    __syncthreads();                       // W stage s resident (drains g2lds)
    f32x4 acc[4] = {};
#pragma unroll
    for (int ks = 0; ks < 8; ++ks)
#pragma unroll
      for (int t = 0; t < 4; ++t) {
        half8 bf = *(const half8*)(Wb + ((size_t)(t * 8 + ks)) * 512 + lane * 8);
        acc[t] = mfma16(a16[ks], bf, acc[t]);
      }
    // Q/K: Lt[row][col], stride 72 halves = 144B (16B-aligned rows)
#pragma unroll
    for (int t = 0; t < 4; ++t) {
      float bval = bias[s * 64 + t * 16 + l16];
#pragma unroll
      for (int r = 0; r < 4; ++r)
        Lt[(wid * 16 + quad * 4 + r) * 72 + t * 16 + l16] =
            (_Float16)((acc[t][r] + bval) * scale);
    }
    __syncthreads();                       // Lt ready AND all waves done w/ Wb
    if (s < 3) {
#pragma unroll
      for (int it = 0; it < 8; ++it)
        g2lds16(WFm + (size_t)(s + 1) * 16384 + it * 2048 + wid * 512 + lane * 8,
                Wb + it * 2048 + wid * 512);
    }
    // stage s covers out-cols s*64..s*64+63 = heads 2s, 2s+1
#pragma unroll
    for (int j = 0; j < 2; ++j) {
      int chunk = j * 256 + tid;
      int row = chunk >> 3, c8 = chunk & 7;
      half8 v = *(const half8*)(Lt + row * 72 + c8 * 8);
      int h = s * 2 + (c8 >> 2);
      size_t wbase = (size_t)((b * 8 + h) * 8 + p) * 32768;
      *(half8*)(outp + wbase + (size_t)(s0 + row) * 32 + (c8 & 3) * 8) = v;
    }
  }
}

// ---------------- V projection: pipelined skeleton + V^T epilogue -----------
// (proven R14)
__global__ __launch_bounds__(256, 3) void vproj_kernel(
    const float* __restrict__ xv, const float* __restrict__ bv,
    _Float16* __restrict__ ws)
{
  __shared__ __align__(16) _Float16 Wb[16384 + 4608];  // 32KB W stage + 9KB Lt
  _Float16* Lt = Wb + 16384;
  const _Float16* WFm = ws + WF_OFF + (size_t)2 * 65536;
  _Float16* outp = ws + VT_OFF;

  int tid = threadIdx.x, lane = tid & 63, wid = tid >> 6;
  int l16 = lane & 15, quad = lane >> 4;
  int m0 = blockIdx.x * 64;
  int b = m0 >> 13, p = (m0 >> 10) & 7, s0 = m0 & 1023;

#pragma unroll
  for (int it = 0; it < 8; ++it)
    g2lds16(WFm + it * 2048 + wid * 512 + lane * 8, Wb + it * 2048 + wid * 512);

  const float* r0 = xv + (size_t)(m0 + wid * 16 + l16) * 256 + quad * 8;
  float4 xa[8][2];
#pragma unroll
  for (int ks = 0; ks < 8; ++ks) {
    xa[ks][0] = *(const float4*)(r0 + ks * 32);
    xa[ks][1] = *(const float4*)(r0 + ks * 32 + 4);
  }
  half8 a16[8];
#pragma unroll
  for (int ks = 0; ks < 8; ++ks) a16[ks] = cvt8(xa[ks][0], xa[ks][1]);

  for (int s = 0; s < 4; ++s) {
    __syncthreads();                       // W stage s resident (drains g2lds)
    f32x4 acc[4] = {};
#pragma unroll
    for (int ks = 0; ks < 8; ++ks)
#pragma unroll
      for (int t = 0; t < 4; ++t) {
        half8 bf = *(const half8*)(Wb + ((size_t)(t * 8 + ks)) * 512 + lane * 8);
        acc[t] = mfma16(a16[ks], bf, acc[t]);
      }
    // V^T: Lt[col][row], stride 72 (rows 16B-aligned)
#pragma unroll
    for (int t = 0; t < 4; ++t) {
      float bval = bv[s * 64 + t * 16 + l16];
      half4 h4;
#pragma unroll
      for (int r = 0; r < 4; ++r) h4[r] = (_Float16)(acc[t][r] + bval);
      *(half4*)(Lt + (t * 16 + l16) * 72 + wid * 16 + quad * 4) = h4;
    }
    __syncthreads();                       // Lt ready AND all waves done w/ Wb
    if (s < 3) {
#pragma unroll
      for (int it = 0; it < 8; ++it)
        g2lds16(WFm + (size_t)(s + 1) * 16384 + it * 2048 + wid * 512 + lane * 8,
                Wb + it * 2048 + wid * 512);
    }
#pragma unroll
    for (int j = 0; j < 2; ++j) {
      int chunk = j * 256 + tid;
      int col = chunk >> 3, r8 = chunk & 7;
      half8 v = *(const half8*)(Lt + col * 72 + r8 * 8);
      int o = s * 64 + col;
      int h = o >> 5, dki = o & 31;
      size_t wbase = (size_t)((b * 8 + h) * 8 + p) * 32768;
      *(half8*)(outp + wbase + (size_t)dki * 1024 + s0 + r8 * 8) = v;
    }
  }
}

// ---------------- attention: wave split-K, exp2-direct, REGISTER P-path -----
__global__ __launch_bounds__(256, 3) void attn_kernel(
    const _Float16* __restrict__ ws, _Float16* __restrict__ ctx)
{
  __shared__ __align__(16) unsigned char smem[18432];  // epilogue only

  int tid = threadIdx.x, lane = tid & 63, wid = tid >> 6;
  int l16 = lane & 15, quad = lane >> 4;
  int w = blockIdx.x & 127, qc = blockIdx.x >> 7;  // XCD-clustered; qc 0..15
  int b = w >> 6, h = (w >> 3) & 7, p = w & 7;
  const _Float16* qhw = ws + QH_OFF + (size_t)w * 32768;
  const _Float16* khw = ws + KH_OFF + (size_t)w * 32768;
  const _Float16* vtw = ws + VT_OFF + (size_t)w * 32768;
  int qrow0 = qc * 64;

  half8 qf[4];
#pragma unroll
  for (int g = 0; g < 4; ++g)
    qf[g] = *(const half8*)(qhw + (size_t)(qrow0 + g * 16 + l16) * 32 + quad * 8);

  // ones A-frag: row m=0 only -> lsum lands in C row 0 (quad==0, reg 0)
  half8 ones = {};
  if (l16 == 0) {
#pragma unroll
    for (int j = 0; j < 8; ++j) ones[j] = (_Float16)1.0f;
  }

  // permuted K row indices: A-row m holds k = (m>>2)*8 + (m&3) (+4 for kc1)
  int kp0 = ((l16 >> 2) << 3) + (l16 & 3);
  int kp1 = kp0 + 4;

  f32x4 Ot[2][4] = {};      // [dk-tile][q-group] O^T partials
  f32x4 Lacc[4] = {};       // lsum partials via ones-row MFMA
  int kbase = wid * 256;

  half8 kc0 = *(const half8*)(khw + (size_t)(kbase + kp0) * 32 + quad * 8);
  half8 kc1 = *(const half8*)(khw + (size_t)(kbase + kp1) * 32 + quad * 8);
  half8 vc0 = *(const half8*)(vtw + (size_t)l16 * 1024 + kbase + quad * 8);
  half8 vc1 = *(const half8*)(vtw + (size_t)(16 + l16) * 1024 + kbase + quad * 8);

  for (int kk = 0; kk < 8; ++kk) {
    int kn = kbase + (((kk + 1) & 7) << 5);
    half8 kn0 = *(const half8*)(khw + (size_t)(kn + kp0) * 32 + quad * 8);
    half8 kn1 = *(const half8*)(khw + (size_t)(kn + kp1) * 32 + quad * 8);
    half8 vn0 = *(const half8*)(vtw + (size_t)l16 * 1024 + kn + quad * 8);
    half8 vn1 = *(const half8*)(vtw + (size_t)(16 + l16) * 1024 + kn + quad * 8);

    f32x4 z = {0.f, 0.f, 0.f, 0.f};
#pragma unroll
    for (int g = 0; g < 4; ++g) {
      f32x4 St0 = mfma16(kc0, qf[g], z);
      f32x4 St1 = mfma16(kc1, qf[g], z);
      f32x4 p0, p1;
#pragma unroll
      for (int r = 0; r < 4; ++r) {
        p0[r] = EXP2F(St0[r]);
        p1[r] = EXP2F(St1[r]);
      }
      half8 pf = cvt8v(p0, p1);          // B[k=quad*8+j][q=l16] directly
      Ot[0][g] = mfma16(vc0, pf, Ot[0][g]);
      Ot[1][g] = mfma16(vc1, pf, Ot[1][g]);
      Lacc[g]  = mfma16(ones, pf, Lacc[g]);
    }
    kc0 = kn0; kc1 = kn1; vc0 = vn0; vc1 = vn1;
  }

  // ---- cross-wave merge (LDS: fp16 Of + Ls) ----
  __syncthreads();
  unsigned int* Of16 = (unsigned int*)smem;        // [4][64][17] u32 (fp16x2)
  float* Ls = (float*)(smem + 17408);              // [4][64]
  if (quad == 0) {
#pragma unroll
    for (int g = 0; g < 4; ++g) Ls[wid * 64 + g * 16 + l16] = Lacc[g][0];
  }
#pragma unroll
  for (int d = 0; d < 2; ++d)
#pragma unroll
    for (int g = 0; g < 4; ++g) {
      int base = wid * 1088 + (g * 16 + l16) * 17 + d * 8 + quad * 2;
      Of16[base]     = pk2(Ot[d][g][0], Ot[d][g][1]);
      Of16[base + 1] = pk2(Ot[d][g][2], Ot[d][g][3]);
    }
  __syncthreads();

  int q = tid >> 2, c = tid & 3;
  float lt = Ls[q] + Ls[64 + q] + Ls[128 + q] + Ls[192 + q];
  float linv = 1.0f / lt;
  union { int i[4]; half8 hh; } u;
#pragma unroll
  for (int jj = 0; jj < 4; ++jj) {
    int idx = q * 17 + c * 4 + jj;
    float sa = 0.f, sb = 0.f;
#pragma unroll
    for (int ww = 0; ww < 4; ++ww) {
      union { unsigned int x; _Float16 h2[2]; } cv;
      cv.x = Of16[ww * 1088 + idx];
      sa += (float)cv.h2[0]; sb += (float)cv.h2[1];
    }
    u.i[jj] = pk2(sa * linv, sb * linv);
  }
  size_t tok = (size_t)(b * 8 + p) * 1024 + qrow0 + q;
  *(half8*)(ctx + tok * 256 + h * 32 + c * 8) = u.hh;
}

// ---------------- output projection: out = ctx @ Wo^T + bo (fp32) -----------
// 4-stage streamed-W structure (proven R13); ctx read once; direct stores.
__global__ __launch_bounds__(256, 4) void oproj_kernel(
    const _Float16* __restrict__ ws, const float* __restrict__ bo,
    float* __restrict__ out)
{
  __shared__ __align__(16) _Float16 Wb[16384];

  int tid = threadIdx.x, lane = tid & 63, wid = tid >> 6;
  int l16 = lane & 15, quad = lane >> 4;
  int m0 = blockIdx.x * 64;
  const _Float16* A = ws + CTX_OFF;
  const _Float16* WF3 = ws + WF_OFF + (size_t)3 * 65536;

#pragma unroll
  for (int it = 0; it < 8; ++it)
    g2lds16(WF3 + it * 2048 + wid * 512 + lane * 8, Wb + it * 2048 + wid * 512);

  const _Float16* r0 = A + (size_t)(m0 + wid * 16 + l16) * 256 + quad * 8;
  half8 a16[8];
#pragma unroll
  for (int ks = 0; ks < 8; ++ks) a16[ks] = *(const half8*)(r0 + ks * 32);

  for (int s = 0; s < 4; ++s) {
    __syncthreads();                       // W stage s resident
    f32x4 acc[4] = {};
#pragma unroll
    for (int ks = 0; ks < 8; ++ks)
#pragma unroll
      for (int t = 0; t < 4; ++t) {
        half8 bf = *(const half8*)(Wb + ((size_t)(t * 8 + ks)) * 512 + lane * 8);
        acc[t] = mfma16(a16[ks], bf, acc[t]);
      }
    __syncthreads();                       // all waves done with Wb
    if (s < 3) {
#pragma unroll
      for (int it = 0; it < 8; ++it)
        g2lds16(WF3 + (size_t)(s + 1) * 16384 + it * 2048 + wid * 512 + lane * 8,
                Wb + it * 2048 + wid * 512);
    }
#pragma unroll
    for (int t = 0; t < 4; ++t) {
      int o = s * 64 + t * 16 + l16;
      float bval = bo[o];
#pragma unroll
      for (int r = 0; r < 4; ++r)
        out[(size_t)(m0 + wid * 16 + quad * 4 + r) * 256 + o] = acc[t][r] + bval;
    }
  }
}

extern "C" void kernel_launch(void* const* d_in, const int* in_sizes, int n_in,
                              void* d_out, int out_size, void* d_ws, size_t ws_size,
                              hipStream_t stream)
{
  const float* q  = (const float*)d_in[0];
  const float* k  = (const float*)d_in[1];
  const float* v  = (const float*)d_in[2];
  const float* Wq = (const float*)d_in[3];
  const float* bq = (const float*)d_in[4];
  const float* Wk = (const float*)d_in[5];
  const float* bk = (const float*)d_in[6];
  const float* Wv = (const float*)d_in[7];
  const float* bv = (const float*)d_in[8];
  const float* Wo = (const float*)d_in[9];
  const float* bo = (const float*)d_in[10];
  _Float16* ws = (_Float16*)d_ws;
  float* out = (float*)d_out;

  prep_kernel<<<128, 256, 0, stream>>>(Wq, Wk, Wv, Wo, ws);
  qkproj_kernel<<<dim3(256, 2), 256, 0, stream>>>(q, k, bq, bk, ws);
  vproj_kernel<<<256, 256, 0, stream>>>(v, bv, ws);
  attn_kernel<<<2048, 256, 0, stream>>>(ws, ws + CTX_OFF);   // 128 win x 16 qc
  oproj_kernel<<<256, 256, 0, stream>>>(ws, bo, out);
}

// Round 8
// 156.545 us; speedup vs baseline: 1.0964x; 1.0286x over previous
//
#include <hip/hip_runtime.h>

// RoutingAttention gfx950 — R17 (= R16 resubmitted; prior round was an
// infra failure, kernel never ran).
// attn+oproj FUSED: block = (b,p,qc), 8 waves = 8 heads, each wave full-K
// (no split-K merge; lsum broadcast via __shfl since C-layout puts q on l16).
// Block assembles 64x256 ctx tile in LDS, then runs the proven 4-stage
// streamed-Wo oproj loop writing fp32 out. Kills the 16MB ctx HBM round-trip
// + one launch + one grid-wide sync. qkproj/vproj/prep identical to R15.
// B=2 P=8 S=1024 C=256 NH=8 DK=32; T=16384.

typedef _Float16 half8 __attribute__((ext_vector_type(8)));
typedef _Float16 half4 __attribute__((ext_vector_type(4)));
typedef float f32x4 __attribute__((ext_vector_type(4)));

#if __has_builtin(__builtin_amdgcn_exp2f)
#define EXP2F(x) __builtin_amdgcn_exp2f(x)
#else
#define EXP2F(x) exp2f(x)
#endif

__device__ __forceinline__ f32x4 mfma16(half8 a, half8 b, f32x4 c) {
  return __builtin_amdgcn_mfma_f32_16x16x32_f16(a, b, c, 0, 0, 0);
}

__device__ __forceinline__ int pk2(float a, float b) {
  auto h = __builtin_amdgcn_cvt_pkrtz(a, b);
  return __builtin_bit_cast(int, h);
}

__device__ __forceinline__ half8 cvt8(float4 f0, float4 f1) {
  union { int i[4]; half8 h; } u;
  u.i[0] = pk2(f0.x, f0.y); u.i[1] = pk2(f0.z, f0.w);
  u.i[2] = pk2(f1.x, f1.y); u.i[3] = pk2(f1.z, f1.w);
  return u.h;
}

__device__ __forceinline__ half8 cvt8v(f32x4 f0, f32x4 f1) {
  union { int i[4]; half8 h; } u;
  u.i[0] = pk2(f0[0], f0[1]); u.i[1] = pk2(f0[2], f0[3]);
  u.i[2] = pk2(f1[0], f1[1]); u.i[3] = pk2(f1[2], f1[3]);
  return u.h;
}

// async global->LDS, 16B per lane; lds dest = wave-uniform base + lane*16
__device__ __forceinline__ void g2lds16(const _Float16* g, _Float16* l) {
  __builtin_amdgcn_global_load_lds(
      (const __attribute__((address_space(1))) void*)g,
      (__attribute__((address_space(3))) void*)l, 16, 0, 0);
}

// ws layout (halves)
static constexpr size_t QH_OFF  = 0;          // (win,s,dk), q scaled log2(e)/sqrt(32)
static constexpr size_t KH_OFF  = 4194304;    // (win,s,dk)
static constexpr size_t VT_OFF  = 8388608;    // (win,dk,s)
static constexpr size_t WF_OFF  = 16777216;   // 4 mats frag-contiguous fp16

// ---------------- W prep: fp32 -> fp16 frag-contiguous ----------------
__global__ __launch_bounds__(256) void prep_kernel(
    const float* __restrict__ wq, const float* __restrict__ wk,
    const float* __restrict__ wv, const float* __restrict__ wo,
    _Float16* __restrict__ ws)
{
  int u = blockIdx.x * 256 + threadIdx.x;          // 0..32767
  int lane = u & 63, ks = (u >> 6) & 7, nt = (u >> 9) & 15, mat = u >> 13;
  const float* W = (mat == 0) ? wq : (mat == 1) ? wk : (mat == 2) ? wv : wo;
  const float* p = W + (size_t)(nt * 16 + (lane & 15)) * 256 + ks * 32 + (lane >> 4) * 8;
  half8 h = cvt8(*(const float4*)p, *(const float4*)(p + 4));
  *(half8*)(ws + WF_OFF + (size_t)u * 8) = h;
}

// ---------------- Q/K projection: pipelined skeleton + Q/K epilogue ---------
__global__ __launch_bounds__(256, 3) void qkproj_kernel(
    const float* __restrict__ xq, const float* __restrict__ xk,
    const float* __restrict__ bq, const float* __restrict__ bk,
    _Float16* __restrict__ ws)
{
  __shared__ __align__(16) _Float16 Wb[16384 + 4608];  // 32KB W stage + 9KB Lt
  _Float16* Lt = Wb + 16384;

  int mode = blockIdx.y;                 // 0=q, 1=k
  const float* X  = mode ? xk : xq;
  const float* bias = mode ? bk : bq;
  const _Float16* WFm = ws + WF_OFF + (size_t)mode * 65536;
  _Float16* outp = ws + (mode ? KH_OFF : QH_OFF);
  const float scale = mode ? 1.0f : 0.2550348654f;  // log2(e)/sqrt(32)

  int tid = threadIdx.x, lane = tid & 63, wid = tid >> 6;
  int l16 = lane & 15, quad = lane >> 4;
  int m0 = blockIdx.x * 64;
  int b = m0 >> 13, p = (m0 >> 10) & 7, s0 = m0 & 1023;

#pragma unroll
  for (int it = 0; it < 8; ++it)
    g2lds16(WFm + it * 2048 + wid * 512 + lane * 8, Wb + it * 2048 + wid * 512);

  const float* r0 = X + (size_t)(m0 + wid * 16 + l16) * 256 + quad * 8;
  float4 xa[8][2];
#pragma unroll
  for (int ks = 0; ks < 8; ++ks) {
    xa[ks][0] = *(const float4*)(r0 + ks * 32);
    xa[ks][1] = *(const float4*)(r0 + ks * 32 + 4);
  }
  half8 a16[8];
#pragma unroll
  for (int ks = 0; ks < 8; ++ks) a16[ks] = cvt8(xa[ks][0], xa[ks][1]);

  for (int s = 0; s < 4; ++s) {
    __syncthreads();                       // W stage s resident (drains g2lds)
    f32x4 acc[4] = {};
#pragma unroll
    for (int ks = 0; ks < 8; ++ks)
#pragma unroll
      for (int t = 0; t < 4; ++t) {
        half8 bf = *(const half8*)(Wb + ((size_t)(t * 8 + ks)) * 512 + lane * 8);
        acc[t] = mfma16(a16[ks], bf, acc[t]);
      }
    // Q/K: Lt[row][col], stride 72 halves = 144B (16B-aligned rows)
#pragma unroll
    for (int t = 0; t < 4; ++t) {
      float bval = bias[s * 64 + t * 16 + l16];
#pragma unroll
      for (int r = 0; r < 4; ++r)
        Lt[(wid * 16 + quad * 4 + r) * 72 + t * 16 + l16] =
            (_Float16)((acc[t][r] + bval) * scale);
    }
    __syncthreads();                       // Lt ready AND all waves done w/ Wb
    if (s < 3) {
#pragma unroll
      for (int it = 0; it < 8; ++it)
        g2lds16(WFm + (size_t)(s + 1) * 16384 + it * 2048 + wid * 512 + lane * 8,
                Wb + it * 2048 + wid * 512);
    }
    // stage s covers out-cols s*64..s*64+63 = heads 2s, 2s+1
#pragma unroll
    for (int j = 0; j < 2; ++j) {
      int chunk = j * 256 + tid;
      int row = chunk >> 3, c8 = chunk & 7;
      half8 v = *(const half8*)(Lt + row * 72 + c8 * 8);
      int h = s * 2 + (c8 >> 2);
      size_t wbase = (size_t)((b * 8 + h) * 8 + p) * 32768;
      *(half8*)(outp + wbase + (size_t)(s0 + row) * 32 + (c8 & 3) * 8) = v;
    }
  }
}

// ---------------- V projection: pipelined skeleton + V^T epilogue -----------
__global__ __launch_bounds__(256, 3) void vproj_kernel(
    const float* __restrict__ xv, const float* __restrict__ bv,
    _Float16* __restrict__ ws)
{
  __shared__ __align__(16) _Float16 Wb[16384 + 4608];  // 32KB W stage + 9KB Lt
  _Float16* Lt = Wb + 16384;
  const _Float16* WFm = ws + WF_OFF + (size_t)2 * 65536;
  _Float16* outp = ws + VT_OFF;

  int tid = threadIdx.x, lane = tid & 63, wid = tid >> 6;
  int l16 = lane & 15, quad = lane >> 4;
  int m0 = blockIdx.x * 64;
  int b = m0 >> 13, p = (m0 >> 10) & 7, s0 = m0 & 1023;

#pragma unroll
  for (int it = 0; it < 8; ++it)
    g2lds16(WFm + it * 2048 + wid * 512 + lane * 8, Wb + it * 2048 + wid * 512);

  const float* r0 = xv + (size_t)(m0 + wid * 16 + l16) * 256 + quad * 8;
  float4 xa[8][2];
#pragma unroll
  for (int ks = 0; ks < 8; ++ks) {
    xa[ks][0] = *(const float4*)(r0 + ks * 32);
    xa[ks][1] = *(const float4*)(r0 + ks * 32 + 4);
  }
  half8 a16[8];
#pragma unroll
  for (int ks = 0; ks < 8; ++ks) a16[ks] = cvt8(xa[ks][0], xa[ks][1]);

  for (int s = 0; s < 4; ++s) {
    __syncthreads();                       // W stage s resident (drains g2lds)
    f32x4 acc[4] = {};
#pragma unroll
    for (int ks = 0; ks < 8; ++ks)
#pragma unroll
      for (int t = 0; t < 4; ++t) {
        half8 bf = *(const half8*)(Wb + ((size_t)(t * 8 + ks)) * 512 + lane * 8);
        acc[t] = mfma16(a16[ks], bf, acc[t]);
      }
    // V^T: Lt[col][row], stride 72 (rows 16B-aligned)
#pragma unroll
    for (int t = 0; t < 4; ++t) {
      float bval = bv[s * 64 + t * 16 + l16];
      half4 h4;
#pragma unroll
      for (int r = 0; r < 4; ++r) h4[r] = (_Float16)(acc[t][r] + bval);
      *(half4*)(Lt + (t * 16 + l16) * 72 + wid * 16 + quad * 4) = h4;
    }
    __syncthreads();                       // Lt ready AND all waves done w/ Wb
    if (s < 3) {
#pragma unroll
      for (int it = 0; it < 8; ++it)
        g2lds16(WFm + (size_t)(s + 1) * 16384 + it * 2048 + wid * 512 + lane * 8,
                Wb + it * 2048 + wid * 512);
    }
#pragma unroll
    for (int j = 0; j < 2; ++j) {
      int chunk = j * 256 + tid;
      int col = chunk >> 3, r8 = chunk & 7;
      half8 v = *(const half8*)(Lt + col * 72 + r8 * 8);
      int o = s * 64 + col;
      int h = o >> 5, dki = o & 31;
      size_t wbase = (size_t)((b * 8 + h) * 8 + p) * 32768;
      *(half8*)(outp + wbase + (size_t)dki * 1024 + s0 + r8 * 8) = v;
    }
  }
}

// ---------------- fused attention + output projection -----------------------
// Block (b,p,qc): 64 tokens, 8 waves = 8 heads, full-K per wave.
// Per wave: register P-path attn (permuted K rows, exp2-direct, ones-row
// lsum). lsum broadcast via __shfl (q lives on l16; lsum on quad-0 lanes).
// Normalized O packed fp16 into LDS ctx tile [64][280], then the proven
// 4-stage streamed-Wo loop (widm rows x widn cols) writes fp32 out.
__global__ __launch_bounds__(512) void attno_kernel(
    const _Float16* __restrict__ ws, const float* __restrict__ bo,
    float* __restrict__ out)
{
  __shared__ __align__(16) _Float16 smem[16384 + 17920];  // Wo 32KB + ctx 35KB
  _Float16* Wb = smem;
  _Float16* ctxL = smem + 16384;                 // [64][280] halves

  int tid = threadIdx.x, lane = tid & 63, wid = tid >> 6;   // wid = head
  int l16 = lane & 15, quad = lane >> 4;
  int w = blockIdx.x & 15, qc = blockIdx.x >> 4; // XCD-clustered (16 apart)
  int b = w >> 3, p = w & 7;
  int qrow0 = qc * 64;
  size_t hb = (size_t)((b * 8 + wid) * 8 + p) * 32768;
  const _Float16* qhw = ws + QH_OFF + hb;
  const _Float16* khw = ws + KH_OFF + hb;
  const _Float16* vtw = ws + VT_OFF + hb;
  const _Float16* WF3 = ws + WF_OFF + (size_t)3 * 65536;

  // stage-0 Wo -> LDS, issued first (resident long before oproj phase)
#pragma unroll
  for (int it = 0; it < 4; ++it)
    g2lds16(WF3 + it * 4096 + wid * 512 + lane * 8, Wb + it * 4096 + wid * 512);

  half8 qf[4];
#pragma unroll
  for (int g = 0; g < 4; ++g)
    qf[g] = *(const half8*)(qhw + (size_t)(qrow0 + g * 16 + l16) * 32 + quad * 8);

  // ones A-frag: row m=0 only -> lsum lands in C row 0 (quad==0, reg 0)
  half8 ones = {};
  if (l16 == 0) {
#pragma unroll
    for (int j = 0; j < 8; ++j) ones[j] = (_Float16)1.0f;
  }

  // permuted K row indices: A-row m holds k = (m>>2)*8 + (m&3) (+4 for kc1)
  int kp0 = ((l16 >> 2) << 3) + (l16 & 3);
  int kp1 = kp0 + 4;

  f32x4 Ot[2][4] = {};      // [dk-tile][q-group] O^T partials
  f32x4 Lacc[4] = {};       // lsum via ones-row MFMA

  half8 kc0 = *(const half8*)(khw + (size_t)kp0 * 32 + quad * 8);
  half8 kc1 = *(const half8*)(khw + (size_t)kp1 * 32 + quad * 8);
  half8 vc0 = *(const half8*)(vtw + (size_t)l16 * 1024 + quad * 8);
  half8 vc1 = *(const half8*)(vtw + (size_t)(16 + l16) * 1024 + quad * 8);

  for (int kk = 0; kk < 32; ++kk) {
    int kn = ((kk + 1) & 31) << 5;
    half8 kn0 = *(const half8*)(khw + (size_t)(kn + kp0) * 32 + quad * 8);
    half8 kn1 = *(const half8*)(khw + (size_t)(kn + kp1) * 32 + quad * 8);
    half8 vn0 = *(const half8*)(vtw + (size_t)l16 * 1024 + kn + quad * 8);
    half8 vn1 = *(const half8*)(vtw + (size_t)(16 + l16) * 1024 + kn + quad * 8);

    f32x4 z = {0.f, 0.f, 0.f, 0.f};
#pragma unroll
    for (int g = 0; g < 4; ++g) {
      f32x4 St0 = mfma16(kc0, qf[g], z);
      f32x4 St1 = mfma16(kc1, qf[g], z);
      f32x4 p0, p1;
#pragma unroll
      for (int r = 0; r < 4; ++r) {
        p0[r] = EXP2F(St0[r]);
        p1[r] = EXP2F(St1[r]);
      }
      half8 pf = cvt8v(p0, p1);          // B[k=quad*8+j][q=l16] directly
      Ot[0][g] = mfma16(vc0, pf, Ot[0][g]);
      Ot[1][g] = mfma16(vc1, pf, Ot[1][g]);
      Lacc[g]  = mfma16(ones, pf, Lacc[g]);
    }
    kc0 = kn0; kc1 = kn1; vc0 = vn0; vc1 = vn1;
  }

  // normalize in-register (lsum for q=g*16+l16 sits on lane l16, reg 0),
  // pack fp16, store into LDS ctx tile: ctxL[q][wid*32 + dk],
  // dk = d*16 + quad*4 + r  (u32 pos = d*8 + quad*2 + r/2)
  unsigned int* cL = (unsigned int*)ctxL;
#pragma unroll
  for (int g = 0; g < 4; ++g) {
    float linv = 1.0f / __shfl(Lacc[g][0], l16);
    int row = g * 16 + l16;
#pragma unroll
    for (int d = 0; d < 2; ++d) {
      int base = row * 140 + wid * 16 + d * 8 + quad * 2;
      cL[base]     = pk2(Ot[d][g][0] * linv, Ot[d][g][1] * linv);
      cL[base + 1] = pk2(Ot[d][g][2] * linv, Ot[d][g][3] * linv);
    }
  }
  __syncthreads();           // ctx tile complete AND Wo stage-0 resident

  // ---- oproj phase: out[64 x 256] = ctx @ Wo^T + bo, Wo streamed 4x64 cols
  int widm = wid >> 1, widn = wid & 1;   // 4 row-groups x 2 col-halves
  int tokbase = (b * 8 + p) * 1024 + qrow0;
  half8 a16[8];
#pragma unroll
  for (int ks = 0; ks < 8; ++ks)
    a16[ks] = *(const half8*)(ctxL + (widm * 16 + l16) * 280 + ks * 32 + quad * 8);

  for (int s = 0; s < 4; ++s) {
    if (s) __syncthreads();              // Wo stage s resident
    f32x4 acc[2] = {};
#pragma unroll
    for (int ks = 0; ks < 8; ++ks)
#pragma unroll
      for (int t = 0; t < 2; ++t) {
        half8 bf = *(const half8*)(Wb + ((size_t)((widn * 2 + t) * 8 + ks)) * 512 + lane * 8);
        acc[t] = mfma16(a16[ks], bf, acc[t]);
      }
    __syncthreads();                     // all waves done with Wb
    if (s < 3) {
#pragma unroll
      for (int it = 0; it < 4; ++it)
        g2lds16(WF3 + (size_t)(s + 1) * 16384 + it * 4096 + wid * 512 + lane * 8,
                Wb + it * 4096 + wid * 512);
    }
#pragma unroll
    for (int t = 0; t < 2; ++t) {
      int o = s * 64 + widn * 32 + t * 16 + l16;
      float bval = bo[o];
#pragma unroll
      for (int r = 0; r < 4; ++r)
        out[(size_t)(tokbase + widm * 16 + quad * 4 + r) * 256 + o] = acc[t][r] + bval;
    }
  }
}

extern "C" void kernel_launch(void* const* d_in, const int* in_sizes, int n_in,
                              void* d_out, int out_size, void* d_ws, size_t ws_size,
                              hipStream_t stream)
{
  const float* q  = (const float*)d_in[0];
  const float* k  = (const float*)d_in[1];
  const float* v  = (const float*)d_in[2];
  const float* Wq = (const float*)d_in[3];
  const float* bq = (const float*)d_in[4];
  const float* Wk = (const float*)d_in[5];
  const float* bk = (const float*)d_in[6];
  const float* Wv = (const float*)d_in[7];
  const float* bv = (const float*)d_in[8];
  const float* Wo = (const float*)d_in[9];
  const float* bo = (const float*)d_in[10];
  _Float16* ws = (_Float16*)d_ws;
  float* out = (float*)d_out;

  prep_kernel<<<128, 256, 0, stream>>>(Wq, Wk, Wv, Wo, ws);
  qkproj_kernel<<<dim3(256, 2), 256, 0, stream>>>(q, k, bq, bk, ws);
  vproj_kernel<<<256, 256, 0, stream>>>(v, bv, ws);
  attno_kernel<<<256, 512, 0, stream>>>(ws, bo, out);   // 16 (b,p) x 16 qc
}

// Round 9
// 149.897 us; speedup vs baseline: 1.1450x; 1.0443x over previous
//
#include <hip/hip_runtime.h>

// RoutingAttention gfx950 — R18.
// qkproj+vproj merged into ONE launch: grid (256,3) = 768 blocks = 256CU x
// 3/CU exactly (no tail under-fill, one less launch boundary). The branch is
// TOP-LEVEL block-uniform with two complete verbatim R15-proven bodies —
// NOT the R11/R12 per-stage in-loop dual epilogue (that CFG is poison).
// attno (fused attn+oproj, R17-proven) and prep unchanged.
// B=2 P=8 S=1024 C=256 NH=8 DK=32; T=16384.

typedef _Float16 half8 __attribute__((ext_vector_type(8)));
typedef _Float16 half4 __attribute__((ext_vector_type(4)));
typedef float f32x4 __attribute__((ext_vector_type(4)));

#if __has_builtin(__builtin_amdgcn_exp2f)
#define EXP2F(x) __builtin_amdgcn_exp2f(x)
#else
#define EXP2F(x) exp2f(x)
#endif

__device__ __forceinline__ f32x4 mfma16(half8 a, half8 b, f32x4 c) {
  return __builtin_amdgcn_mfma_f32_16x16x32_f16(a, b, c, 0, 0, 0);
}

__device__ __forceinline__ int pk2(float a, float b) {
  auto h = __builtin_amdgcn_cvt_pkrtz(a, b);
  return __builtin_bit_cast(int, h);
}

__device__ __forceinline__ half8 cvt8(float4 f0, float4 f1) {
  union { int i[4]; half8 h; } u;
  u.i[0] = pk2(f0.x, f0.y); u.i[1] = pk2(f0.z, f0.w);
  u.i[2] = pk2(f1.x, f1.y); u.i[3] = pk2(f1.z, f1.w);
  return u.h;
}

__device__ __forceinline__ half8 cvt8v(f32x4 f0, f32x4 f1) {
  union { int i[4]; half8 h; } u;
  u.i[0] = pk2(f0[0], f0[1]); u.i[1] = pk2(f0[2], f0[3]);
  u.i[2] = pk2(f1[0], f1[1]); u.i[3] = pk2(f1[2], f1[3]);
  return u.h;
}

// async global->LDS, 16B per lane; lds dest = wave-uniform base + lane*16
__device__ __forceinline__ void g2lds16(const _Float16* g, _Float16* l) {
  __builtin_amdgcn_global_load_lds(
      (const __attribute__((address_space(1))) void*)g,
      (__attribute__((address_space(3))) void*)l, 16, 0, 0);
}

// ws layout (halves)
static constexpr size_t QH_OFF  = 0;          // (win,s,dk), q scaled log2(e)/sqrt(32)
static constexpr size_t KH_OFF  = 4194304;    // (win,s,dk)
static constexpr size_t VT_OFF  = 8388608;    // (win,dk,s)
static constexpr size_t WF_OFF  = 16777216;   // 4 mats frag-contiguous fp16

// ---------------- W prep: fp32 -> fp16 frag-contiguous ----------------
__global__ __launch_bounds__(256) void prep_kernel(
    const float* __restrict__ wq, const float* __restrict__ wk,
    const float* __restrict__ wv, const float* __restrict__ wo,
    _Float16* __restrict__ ws)
{
  int u = blockIdx.x * 256 + threadIdx.x;          // 0..32767
  int lane = u & 63, ks = (u >> 6) & 7, nt = (u >> 9) & 15, mat = u >> 13;
  const float* W = (mat == 0) ? wq : (mat == 1) ? wk : (mat == 2) ? wv : wo;
  const float* p = W + (size_t)(nt * 16 + (lane & 15)) * 256 + ks * 32 + (lane >> 4) * 8;
  half8 h = cvt8(*(const float4*)p, *(const float4*)(p + 4));
  *(half8*)(ws + WF_OFF + (size_t)u * 8) = h;
}

// ---------------- Q/K/V projection: ONE launch, top-level mode split --------
// mode = blockIdx.y: 0=q, 1=k (row-layout epilogue), 2=v (V^T epilogue).
// Each branch is the verbatim R15-proven single-epilogue pipelined body.
__global__ __launch_bounds__(256, 3) void proj_kernel(
    const float* __restrict__ xq, const float* __restrict__ xk,
    const float* __restrict__ xv,
    const float* __restrict__ bq, const float* __restrict__ bk,
    const float* __restrict__ bv,
    _Float16* __restrict__ ws)
{
  __shared__ __align__(16) _Float16 Wb[16384 + 4608];  // 32KB W stage + 9KB Lt

  int mode = blockIdx.y;
  if (mode < 2) {
    // ================= Q/K body (verbatim R15 qkproj) =================
    _Float16* Lt = Wb + 16384;
    const float* X  = mode ? xk : xq;
    const float* bias = mode ? bk : bq;
    const _Float16* WFm = ws + WF_OFF + (size_t)mode * 65536;
    _Float16* outp = ws + (mode ? KH_OFF : QH_OFF);
    const float scale = mode ? 1.0f : 0.2550348654f;  // log2(e)/sqrt(32)

    int tid = threadIdx.x, lane = tid & 63, wid = tid >> 6;
    int l16 = lane & 15, quad = lane >> 4;
    int m0 = blockIdx.x * 64;
    int b = m0 >> 13, p = (m0 >> 10) & 7, s0 = m0 & 1023;

#pragma unroll
    for (int it = 0; it < 8; ++it)
      g2lds16(WFm + it * 2048 + wid * 512 + lane * 8, Wb + it * 2048 + wid * 512);

    const float* r0 = X + (size_t)(m0 + wid * 16 + l16) * 256 + quad * 8;
    float4 xa[8][2];
#pragma unroll
    for (int ks = 0; ks < 8; ++ks) {
      xa[ks][0] = *(const float4*)(r0 + ks * 32);
      xa[ks][1] = *(const float4*)(r0 + ks * 32 + 4);
    }
    half8 a16[8];
#pragma unroll
    for (int ks = 0; ks < 8; ++ks) a16[ks] = cvt8(xa[ks][0], xa[ks][1]);

    for (int s = 0; s < 4; ++s) {
      __syncthreads();                       // W stage s resident
      f32x4 acc[4] = {};
#pragma unroll
      for (int ks = 0; ks < 8; ++ks)
#pragma unroll
        for (int t = 0; t < 4; ++t) {
          half8 bf = *(const half8*)(Wb + ((size_t)(t * 8 + ks)) * 512 + lane * 8);
          acc[t] = mfma16(a16[ks], bf, acc[t]);
        }
      // Q/K: Lt[row][col], stride 72 halves = 144B (16B-aligned rows)
#pragma unroll
      for (int t = 0; t < 4; ++t) {
        float bval = bias[s * 64 + t * 16 + l16];
#pragma unroll
        for (int r = 0; r < 4; ++r)
          Lt[(wid * 16 + quad * 4 + r) * 72 + t * 16 + l16] =
              (_Float16)((acc[t][r] + bval) * scale);
      }
      __syncthreads();                       // Lt ready AND all waves done w/ Wb
      if (s < 3) {
#pragma unroll
        for (int it = 0; it < 8; ++it)
          g2lds16(WFm + (size_t)(s + 1) * 16384 + it * 2048 + wid * 512 + lane * 8,
                  Wb + it * 2048 + wid * 512);
      }
      // stage s covers out-cols s*64..s*64+63 = heads 2s, 2s+1
#pragma unroll
      for (int j = 0; j < 2; ++j) {
        int chunk = j * 256 + tid;
        int row = chunk >> 3, c8 = chunk & 7;
        half8 v = *(const half8*)(Lt + row * 72 + c8 * 8);
        int h = s * 2 + (c8 >> 2);
        size_t wbase = (size_t)((b * 8 + h) * 8 + p) * 32768;
        *(half8*)(outp + wbase + (size_t)(s0 + row) * 32 + (c8 & 3) * 8) = v;
      }
    }
  } else {
    // ================= V body (verbatim R15 vproj) =================
    _Float16* Lt = Wb + 16384;
    const _Float16* WFm = ws + WF_OFF + (size_t)2 * 65536;
    _Float16* outp = ws + VT_OFF;

    int tid = threadIdx.x, lane = tid & 63, wid = tid >> 6;
    int l16 = lane & 15, quad = lane >> 4;
    int m0 = blockIdx.x * 64;
    int b = m0 >> 13, p = (m0 >> 10) & 7, s0 = m0 & 1023;

#pragma unroll
    for (int it = 0; it < 8; ++it)
      g2lds16(WFm + it * 2048 + wid * 512 + lane * 8, Wb + it * 2048 + wid * 512);

    const float* r0 = xv + (size_t)(m0 + wid * 16 + l16) * 256 + quad * 8;
    float4 xa[8][2];
#pragma unroll
    for (int ks = 0; ks < 8; ++ks) {
      xa[ks][0] = *(const float4*)(r0 + ks * 32);
      xa[ks][1] = *(const float4*)(r0 + ks * 32 + 4);
    }
    half8 a16[8];
#pragma unroll
    for (int ks = 0; ks < 8; ++ks) a16[ks] = cvt8(xa[ks][0], xa[ks][1]);

    for (int s = 0; s < 4; ++s) {
      __syncthreads();                       // W stage s resident
      f32x4 acc[4] = {};
#pragma unroll
      for (int ks = 0; ks < 8; ++ks)
#pragma unroll
        for (int t = 0; t < 4; ++t) {
          half8 bf = *(const half8*)(Wb + ((size_t)(t * 8 + ks)) * 512 + lane * 8);
          acc[t] = mfma16(a16[ks], bf, acc[t]);
        }
      // V^T: Lt[col][row], stride 72 (rows 16B-aligned)
#pragma unroll
      for (int t = 0; t < 4; ++t) {
        float bval = bv[s * 64 + t * 16 + l16];
        half4 h4;
#pragma unroll
        for (int r = 0; r < 4; ++r) h4[r] = (_Float16)(acc[t][r] + bval);
        *(half4*)(Lt + (t * 16 + l16) * 72 + wid * 16 + quad * 4) = h4;
      }
      __syncthreads();                       // Lt ready AND all waves done w/ Wb
      if (s < 3) {
#pragma unroll
        for (int it = 0; it < 8; ++it)
          g2lds16(WFm + (size_t)(s + 1) * 16384 + it * 2048 + wid * 512 + lane * 8,
                  Wb + it * 2048 + wid * 512);
      }
#pragma unroll
      for (int j = 0; j < 2; ++j) {
        int chunk = j * 256 + tid;
        int col = chunk >> 3, r8 = chunk & 7;
        half8 v = *(const half8*)(Lt + col * 72 + r8 * 8);
        int o = s * 64 + col;
        int h = o >> 5, dki = o & 31;
        size_t wbase = (size_t)((b * 8 + h) * 8 + p) * 32768;
        *(half8*)(outp + wbase + (size_t)dki * 1024 + s0 + r8 * 8) = v;
      }
    }
  }
}

// ---------------- fused attention + output projection (R17-proven) ----------
// Block (b,p,qc): 64 tokens, 8 waves = 8 heads, full-K per wave.
__global__ __launch_bounds__(512) void attno_kernel(
    const _Float16* __restrict__ ws, const float* __restrict__ bo,
    float* __restrict__ out)
{
  __shared__ __align__(16) _Float16 smem[16384 + 17920];  // Wo 32KB + ctx 35KB
  _Float16* Wb = smem;
  _Float16* ctxL = smem + 16384;                 // [64][280] halves

  int tid = threadIdx.x, lane = tid & 63, wid = tid >> 6;   // wid = head
  int l16 = lane & 15, quad = lane >> 4;
  int w = blockIdx.x & 15, qc = blockIdx.x >> 4; // XCD-clustered (16 apart)
  int b = w >> 3, p = w & 7;
  int qrow0 = qc * 64;
  size_t hb = (size_t)((b * 8 + wid) * 8 + p) * 32768;
  const _Float16* qhw = ws + QH_OFF + hb;
  const _Float16* khw = ws + KH_OFF + hb;
  const _Float16* vtw = ws + VT_OFF + hb;
  const _Float16* WF3 = ws + WF_OFF + (size_t)3 * 65536;

  // stage-0 Wo -> LDS, issued first (resident long before oproj phase)
#pragma unroll
  for (int it = 0; it < 4; ++it)
    g2lds16(WF3 + it * 4096 + wid * 512 + lane * 8, Wb + it * 4096 + wid * 512);

  half8 qf[4];
#pragma unroll
  for (int g = 0; g < 4; ++g)
    qf[g] = *(const half8*)(qhw + (size_t)(qrow0 + g * 16 + l16) * 32 + quad * 8);

  // ones A-frag: row m=0 only -> lsum lands in C row 0 (quad==0, reg 0)
  half8 ones = {};
  if (l16 == 0) {
#pragma unroll
    for (int j = 0; j < 8; ++j) ones[j] = (_Float16)1.0f;
  }

  // permuted K row indices: A-row m holds k = (m>>2)*8 + (m&3) (+4 for kc1)
  int kp0 = ((l16 >> 2) << 3) + (l16 & 3);
  int kp1 = kp0 + 4;

  f32x4 Ot[2][4] = {};      // [dk-tile][q-group] O^T partials
  f32x4 Lacc[4] = {};       // lsum via ones-row MFMA

  half8 kc0 = *(const half8*)(khw + (size_t)kp0 * 32 + quad * 8);
  half8 kc1 = *(const half8*)(khw + (size_t)kp1 * 32 + quad * 8);
  half8 vc0 = *(const half8*)(vtw + (size_t)l16 * 1024 + quad * 8);
  half8 vc1 = *(const half8*)(vtw + (size_t)(16 + l16) * 1024 + quad * 8);

  for (int kk = 0; kk < 32; ++kk) {
    int kn = ((kk + 1) & 31) << 5;
    half8 kn0 = *(const half8*)(khw + (size_t)(kn + kp0) * 32 + quad * 8);
    half8 kn1 = *(const half8*)(khw + (size_t)(kn + kp1) * 32 + quad * 8);
    half8 vn0 = *(const half8*)(vtw + (size_t)l16 * 1024 + kn + quad * 8);
    half8 vn1 = *(const half8*)(vtw + (size_t)(16 + l16) * 1024 + kn + quad * 8);

    f32x4 z = {0.f, 0.f, 0.f, 0.f};
#pragma unroll
    for (int g = 0; g < 4; ++g) {
      f32x4 St0 = mfma16(kc0, qf[g], z);
      f32x4 St1 = mfma16(kc1, qf[g], z);
      f32x4 p0, p1;
#pragma unroll
      for (int r = 0; r < 4; ++r) {
        p0[r] = EXP2F(St0[r]);
        p1[r] = EXP2F(St1[r]);
      }
      half8 pf = cvt8v(p0, p1);          // B[k=quad*8+j][q=l16] directly
      Ot[0][g] = mfma16(vc0, pf, Ot[0][g]);
      Ot[1][g] = mfma16(vc1, pf, Ot[1][g]);
      Lacc[g]  = mfma16(ones, pf, Lacc[g]);
    }
    kc0 = kn0; kc1 = kn1; vc0 = vn0; vc1 = vn1;
  }

  // normalize in-register (lsum for q=g*16+l16 sits on lane l16, reg 0),
  // pack fp16, store into LDS ctx tile: ctxL[q][wid*32 + dk]
  unsigned int* cL = (unsigned int*)ctxL;
#pragma unroll
  for (int g = 0; g < 4; ++g) {
    float linv = 1.0f / __shfl(Lacc[g][0], l16);
    int row = g * 16 + l16;
#pragma unroll
    for (int d = 0; d < 2; ++d) {
      int base = row * 140 + wid * 16 + d * 8 + quad * 2;
      cL[base]     = pk2(Ot[d][g][0] * linv, Ot[d][g][1] * linv);
      cL[base + 1] = pk2(Ot[d][g][2] * linv, Ot[d][g][3] * linv);
    }
  }
  __syncthreads();           // ctx tile complete AND Wo stage-0 resident

  // ---- oproj phase: out[64 x 256] = ctx @ Wo^T + bo, Wo streamed 4x64 cols
  int widm = wid >> 1, widn = wid & 1;   // 4 row-groups x 2 col-halves
  int tokbase = (b * 8 + p) * 1024 + qrow0;
  half8 a16[8];
#pragma unroll
  for (int ks = 0; ks < 8; ++ks)
    a16[ks] = *(const half8*)(ctxL + (widm * 16 + l16) * 280 + ks * 32 + quad * 8);

  for (int s = 0; s < 4; ++s) {
    if (s) __syncthreads();              // Wo stage s resident
    f32x4 acc[2] = {};
#pragma unroll
    for (int ks = 0; ks < 8; ++ks)
#pragma unroll
      for (int t = 0; t < 2; ++t) {
        half8 bf = *(const half8*)(Wb + ((size_t)((widn * 2 + t) * 8 + ks)) * 512 + lane * 8);
        acc[t] = mfma16(a16[ks], bf, acc[t]);
      }
    __syncthreads();                     // all waves done with Wb
    if (s < 3) {
#pragma unroll
      for (int it = 0; it < 4; ++it)
        g2lds16(WF3 + (size_t)(s + 1) * 16384 + it * 4096 + wid * 512 + lane * 8,
                Wb + it * 4096 + wid * 512);
    }
#pragma unroll
    for (int t = 0; t < 2; ++t) {
      int o = s * 64 + widn * 32 + t * 16 + l16;
      float bval = bo[o];
#pragma unroll
      for (int r = 0; r < 4; ++r)
        out[(size_t)(tokbase + widm * 16 + quad * 4 + r) * 256 + o] = acc[t][r] + bval;
    }
  }
}

extern "C" void kernel_launch(void* const* d_in, const int* in_sizes, int n_in,
                              void* d_out, int out_size, void* d_ws, size_t ws_size,
                              hipStream_t stream)
{
  const float* q  = (const float*)d_in[0];
  const float* k  = (const float*)d_in[1];
  const float* v  = (const float*)d_in[2];
  const float* Wq = (const float*)d_in[3];
  const float* bq = (const float*)d_in[4];
  const float* Wk = (const float*)d_in[5];
  const float* bk = (const float*)d_in[6];
  const float* Wv = (const float*)d_in[7];
  const float* bv = (const float*)d_in[8];
  const float* Wo = (const float*)d_in[9];
  const float* bo = (const float*)d_in[10];
  _Float16* ws = (_Float16*)d_ws;
  float* out = (float*)d_out;

  prep_kernel<<<128, 256, 0, stream>>>(Wq, Wk, Wv, Wo, ws);
  proj_kernel<<<dim3(256, 3), 256, 0, stream>>>(q, k, v, bq, bk, bv, ws);
  attno_kernel<<<256, 512, 0, stream>>>(ws, bo, out);   // 16 (b,p) x 16 qc
}